// Round 1
// baseline (622.027 us; speedup 1.0000x reference)
//
#include <hip/hip_runtime.h>
#include <hip/hip_bf16.h>

#define NEG 0.2f

// ---------------------------------------------------------------- CSR build
__global__ void k_zero(int* __restrict__ p, int n) {
    int i = blockIdx.x * 256 + threadIdx.x;
    if (i < n) p[i] = 0;
}

__global__ void k_count(const int* __restrict__ ei, int* __restrict__ deg,
                        int E_, int n) {
    int e = blockIdx.x * 256 + threadIdx.x;
    int tot = E_ + n;
    if (e >= tot) return;
    int d = (e < E_) ? ei[E_ + e] : (e - E_);
    atomicAdd(&deg[d], 1);
}

// single-block shuffle-based exclusive scan over deg[0..n) -> offs, cursor
__global__ __launch_bounds__(1024) void k_scan(const int* __restrict__ deg,
                                               int* __restrict__ offs,
                                               int* __restrict__ cursor, int n) {
    __shared__ int wsum[16];
    __shared__ int carry_s;
    int tid = threadIdx.x, lane = tid & 63, w = tid >> 6;
    if (tid == 0) carry_s = 0;
    __syncthreads();
    for (int base = 0; base < n; base += 1024) {
        int i = base + tid;
        int val = (i < n) ? deg[i] : 0;
        int incl = val;
        #pragma unroll
        for (int off = 1; off < 64; off <<= 1) {
            int t = __shfl_up(incl, off, 64);
            if (lane >= off) incl += t;
        }
        if (lane == 63) wsum[w] = incl;
        __syncthreads();
        int carry = carry_s;
        if (w == 0) {
            int s = (lane < 16) ? wsum[lane] : 0;
            #pragma unroll
            for (int off = 1; off < 16; off <<= 1) {
                int t = __shfl_up(s, off, 64);
                if (lane >= off) s += t;
            }
            if (lane < 16) wsum[lane] = s;
        }
        __syncthreads();
        int woff = (w > 0) ? wsum[w - 1] : 0;
        int excl = carry + woff + incl - val;
        if (i < n) { offs[i] = excl; cursor[i] = excl; }
        __syncthreads();
        if (tid == 0) carry_s = carry + wsum[15];
        __syncthreads();
    }
    if (threadIdx.x == 0) offs[n] = carry_s;
}

__global__ void k_scatter(const int* __restrict__ ei, int* __restrict__ cursor,
                          int* __restrict__ csr, int E_, int n) {
    int e = blockIdx.x * 256 + threadIdx.x;
    int tot = E_ + n;
    if (e >= tot) return;
    int s, d;
    if (e < E_) { s = ei[e]; d = ei[E_ + e]; } else { s = d = e - E_; }
    int pos = atomicAdd(&cursor[d], 1);
    csr[pos] = s;
}

// ---------------------------------------------------------------- GEMM1
// h1[M,512] = x[M,128] @ W[128,512], fp32, 64x64 tile, whole K in LDS.
__global__ __launch_bounds__(256) void k_gemm1(const float* __restrict__ x,
                                               const float* __restrict__ W,
                                               float* __restrict__ h1, int n) {
    __shared__ float xs[128][68];   // xs[k][r] = x[row0+r][k]
    __shared__ float wl[128][68];   // wl[k][c] = W[k][col0+c]
    int tid = threadIdx.x;
    int row0 = blockIdx.x * 64;
    int col0 = blockIdx.y * 64;
    {   // stage x (transposed)
        int r = tid >> 2, q = tid & 3;
        int gr = row0 + r;
        const float* xp = x + (size_t)gr * 128;
        #pragma unroll
        for (int j = 0; j < 8; j++) {
            int k = (q + j * 4) * 4;
            float4 v = (gr < n) ? *(const float4*)(xp + k) : make_float4(0, 0, 0, 0);
            xs[k + 0][r] = v.x; xs[k + 1][r] = v.y;
            xs[k + 2][r] = v.z; xs[k + 3][r] = v.w;
        }
    }
    {   // stage W
        int c = (tid & 15) * 4;
        int k0 = tid >> 4;
        #pragma unroll
        for (int j = 0; j < 8; j++) {
            int k = k0 + j * 16;
            *(float4*)&wl[k][c] = *(const float4*)(W + (size_t)k * 512 + col0 + c);
        }
    }
    __syncthreads();
    int tx = tid & 15, ty = tid >> 4;
    float acc[4][4] = {};
    #pragma unroll 8
    for (int k = 0; k < 128; k++) {
        float4 a = *(const float4*)&xs[k][ty * 4];
        float4 b = *(const float4*)&wl[k][tx * 4];
        float ar[4] = {a.x, a.y, a.z, a.w};
        float br[4] = {b.x, b.y, b.z, b.w};
        #pragma unroll
        for (int i = 0; i < 4; i++)
            #pragma unroll
            for (int j = 0; j < 4; j++)
                acc[i][j] = fmaf(ar[i], br[j], acc[i][j]);
    }
    int gr = row0 + ty * 4, gc = col0 + tx * 4;
    #pragma unroll
    for (int i = 0; i < 4; i++) {
        if (gr + i < n)
            *(float4*)(h1 + (size_t)(gr + i) * 512 + gc) =
                make_float4(acc[i][0], acc[i][1], acc[i][2], acc[i][3]);
    }
}

// ---------------------------------------------------------------- alpha1
// as1[v,h] = dot(h1[v,h,:], a_src[h,:]), same for ad1. One wave per node.
__global__ __launch_bounds__(256) void k_alpha1(const float* __restrict__ h1,
                                                const float* __restrict__ a_src,
                                                const float* __restrict__ a_dst,
                                                float* __restrict__ as1,
                                                float* __restrict__ ad1, int n) {
    int lane = threadIdx.x & 63;
    int v = blockIdx.x * 4 + (threadIdx.x >> 6);
    if (v >= n) return;
    const float4* hp = (const float4*)(h1 + (size_t)v * 512) + lane * 2;
    float4 ha = hp[0], hb = hp[1];
    const float4* sp = (const float4*)a_src + lane * 2;
    float4 sa = sp[0], sb = sp[1];
    const float4* dp = (const float4*)a_dst + lane * 2;
    float4 da = dp[0], db = dp[1];
    float ps = ha.x * sa.x + ha.y * sa.y + ha.z * sa.z + ha.w * sa.w
             + hb.x * sb.x + hb.y * sb.y + hb.z * sb.z + hb.w * sb.w;
    float pd = ha.x * da.x + ha.y * da.y + ha.z * da.z + ha.w * da.w
             + hb.x * db.x + hb.y * db.y + hb.z * db.z + hb.w * db.w;
    #pragma unroll
    for (int off = 1; off < 8; off <<= 1) {
        ps += __shfl_xor(ps, off, 64);
        pd += __shfl_xor(pd, off, 64);
    }
    if ((lane & 7) == 0) {
        as1[v * 8 + (lane >> 3)] = ps;
        ad1[v * 8 + (lane >> 3)] = pd;
    }
}

// ---------------------------------------------------------------- agg layer 1
// One wave per dst node. Pass1: lane-parallel online softmax (8 heads).
// Pass2: wave-per-edge, lane covers channels [8*lane, 8*lane+8) (head=lane>>3).
// Epilogue: +b1, ELU, store x2.
__global__ __launch_bounds__(256) void k_agg1(const float* __restrict__ h1,
                                              const float* __restrict__ as1,
                                              const float* __restrict__ ad1,
                                              const float* __restrict__ b1,
                                              const int* __restrict__ offs,
                                              const int* __restrict__ csr,
                                              float* __restrict__ x2, int n) {
    int lane = threadIdx.x & 63;
    int v = blockIdx.x * 4 + (threadIdx.x >> 6);
    if (v >= n) return;
    int s0 = offs[v], s1 = offs[v + 1];
    float adv[8];
    {
        float4 a = *(const float4*)(ad1 + v * 8);
        float4 b = *(const float4*)(ad1 + v * 8 + 4);
        adv[0] = a.x; adv[1] = a.y; adv[2] = a.z; adv[3] = a.w;
        adv[4] = b.x; adv[5] = b.y; adv[6] = b.z; adv[7] = b.w;
    }
    float m[8], s[8];
    #pragma unroll
    for (int h = 0; h < 8; h++) { m[h] = -1e30f; s[h] = 0.f; }
    for (int i = s0 + lane; i < s1; i += 64) {
        int u = csr[i];
        float4 a = *(const float4*)(as1 + u * 8);
        float4 b = *(const float4*)(as1 + u * 8 + 4);
        float ev[8] = {a.x, a.y, a.z, a.w, b.x, b.y, b.z, b.w};
        #pragma unroll
        for (int h = 0; h < 8; h++) {
            float e = ev[h] + adv[h];
            e = (e >= 0.f) ? e : NEG * e;
            float nm = fmaxf(m[h], e);
            s[h] = s[h] * __expf(m[h] - nm) + __expf(e - nm);
            m[h] = nm;
        }
    }
    #pragma unroll
    for (int off = 1; off < 64; off <<= 1) {
        #pragma unroll
        for (int h = 0; h < 8; h++) {
            float om = __shfl_xor(m[h], off, 64);
            float os = __shfl_xor(s[h], off, 64);
            float nm = fmaxf(m[h], om);
            s[h] = s[h] * __expf(m[h] - nm) + os * __expf(om - nm);
            m[h] = nm;
        }
    }
    int head = lane >> 3;
    float mh = m[0], sh = s[0], adh = adv[0];
    #pragma unroll
    for (int h = 1; h < 8; h++)
        if (head == h) { mh = m[h]; sh = s[h]; adh = adv[h]; }
    float inv = 1.0f / sh;
    float4 acc0 = make_float4(0, 0, 0, 0), acc1 = make_float4(0, 0, 0, 0);
    for (int i = s0; i < s1; i++) {
        int u = csr[i];
        float e = as1[u * 8 + head] + adh;
        e = (e >= 0.f) ? e : NEG * e;
        float w = __expf(e - mh) * inv;
        const float4* hp = (const float4*)(h1 + (size_t)u * 512) + lane * 2;
        float4 ha = hp[0], hb = hp[1];
        acc0.x = fmaf(w, ha.x, acc0.x); acc0.y = fmaf(w, ha.y, acc0.y);
        acc0.z = fmaf(w, ha.z, acc0.z); acc0.w = fmaf(w, ha.w, acc0.w);
        acc1.x = fmaf(w, hb.x, acc1.x); acc1.y = fmaf(w, hb.y, acc1.y);
        acc1.z = fmaf(w, hb.z, acc1.z); acc1.w = fmaf(w, hb.w, acc1.w);
    }
    int c = lane * 8;
    float4 ba = *(const float4*)(b1 + c);
    float4 bb = *(const float4*)(b1 + c + 4);
    float o[8] = {acc0.x + ba.x, acc0.y + ba.y, acc0.z + ba.z, acc0.w + ba.w,
                  acc1.x + bb.x, acc1.y + bb.y, acc1.z + bb.z, acc1.w + bb.w};
    #pragma unroll
    for (int j = 0; j < 8; j++)
        o[j] = (o[j] > 0.f) ? o[j] : (__expf(o[j]) - 1.0f);
    float4* op = (float4*)(x2 + (size_t)v * 512) + lane * 2;
    op[0] = make_float4(o[0], o[1], o[2], o[3]);
    op[1] = make_float4(o[4], o[5], o[6], o[7]);
}

// ---------------------------------------------------------------- layer2 prep
// h2[v,:2] = x2[v,:] @ W2;  as2/ad2 scalars. One wave per node.
__global__ __launch_bounds__(256) void k_l2prep(const float* __restrict__ x2,
                                                const float* __restrict__ W2,
                                                const float* __restrict__ a_src2,
                                                const float* __restrict__ a_dst2,
                                                float* __restrict__ h2,
                                                float* __restrict__ as2,
                                                float* __restrict__ ad2, int n) {
    int lane = threadIdx.x & 63;
    int v = blockIdx.x * 4 + (threadIdx.x >> 6);
    if (v >= n) return;
    const float4* xp = (const float4*)(x2 + (size_t)v * 512) + lane * 2;
    float4 xa = xp[0], xb = xp[1];
    int c = lane * 8;
    const float4* wp = (const float4*)(W2 + c * 2);
    float4 w0 = wp[0], w1 = wp[1], w2 = wp[2], w3 = wp[3];
    float p0 = xa.x * w0.x + xa.y * w0.z + xa.z * w1.x + xa.w * w1.z
             + xb.x * w2.x + xb.y * w2.z + xb.z * w3.x + xb.w * w3.z;
    float p1 = xa.x * w0.y + xa.y * w0.w + xa.z * w1.y + xa.w * w1.w
             + xb.x * w2.y + xb.y * w2.w + xb.z * w3.y + xb.w * w3.w;
    #pragma unroll
    for (int off = 1; off < 64; off <<= 1) {
        p0 += __shfl_xor(p0, off, 64);
        p1 += __shfl_xor(p1, off, 64);
    }
    if (lane == 0) {
        h2[2 * v] = p0; h2[2 * v + 1] = p1;
        as2[v] = p0 * a_src2[0] + p1 * a_src2[1];
        ad2[v] = p0 * a_dst2[0] + p1 * a_dst2[1];
    }
}

// ---------------------------------------------------------------- agg layer 2
// Single-pass online softmax-weighted sum, one wave per node, 2 channels.
__global__ __launch_bounds__(256) void k_agg2(const float* __restrict__ h2,
                                              const float* __restrict__ as2,
                                              const float* __restrict__ ad2,
                                              const float* __restrict__ b2,
                                              const int* __restrict__ offs,
                                              const int* __restrict__ csr,
                                              float* __restrict__ out, int n) {
    int lane = threadIdx.x & 63;
    int v = blockIdx.x * 4 + (threadIdx.x >> 6);
    if (v >= n) return;
    int s0 = offs[v], s1 = offs[v + 1];
    float adv = ad2[v];
    float m = -1e30f, s = 0.f, a0 = 0.f, a1 = 0.f;
    for (int i = s0 + lane; i < s1; i += 64) {
        int u = csr[i];
        float e = as2[u] + adv;
        e = (e >= 0.f) ? e : NEG * e;
        float nm = fmaxf(m, e);
        float sc = __expf(m - nm), w = __expf(e - nm);
        s = s * sc + w;
        a0 = a0 * sc + w * h2[2 * u];
        a1 = a1 * sc + w * h2[2 * u + 1];
        m = nm;
    }
    #pragma unroll
    for (int off = 1; off < 64; off <<= 1) {
        float om = __shfl_xor(m, off, 64);
        float os = __shfl_xor(s, off, 64);
        float oa0 = __shfl_xor(a0, off, 64);
        float oa1 = __shfl_xor(a1, off, 64);
        float nm = fmaxf(m, om);
        float e0 = __expf(m - nm), e1 = __expf(om - nm);
        s = s * e0 + os * e1;
        a0 = a0 * e0 + oa0 * e1;
        a1 = a1 * e0 + oa1 * e1;
        m = nm;
    }
    if (lane == 0) {
        float inv = 1.0f / s;
        out[2 * v]     = a0 * inv + b2[0];
        out[2 * v + 1] = a1 * inv + b2[1];
    }
}

// ---------------------------------------------------------------- launch
extern "C" void kernel_launch(void* const* d_in, const int* in_sizes, int n_in,
                              void* d_out, int out_size, void* d_ws, size_t ws_size,
                              hipStream_t stream) {
    const float* x      = (const float*)d_in[0];
    const int*   ei     = (const int*)d_in[1];
    const float* W1     = (const float*)d_in[2];
    const float* a_src1 = (const float*)d_in[3];
    const float* a_dst1 = (const float*)d_in[4];
    const float* b1     = (const float*)d_in[5];
    const float* W2     = (const float*)d_in[6];
    const float* a_src2 = (const float*)d_in[7];
    const float* a_dst2 = (const float*)d_in[8];
    const float* b2     = (const float*)d_in[9];
    float* out = (float*)d_out;

    int n  = in_sizes[0] / 128;   // 50000
    int E_ = in_sizes[1] / 2;     // 800000
    int tot = E_ + n;

    char* w = (char*)d_ws;
    auto alloc = [&](size_t bytes) {
        char* p = w; w += (bytes + 255) & ~(size_t)255; return p;
    };
    int*   deg    = (int*)alloc((size_t)n * 4);
    int*   offs   = (int*)alloc((size_t)(n + 1) * 4);
    int*   cursor = (int*)alloc((size_t)n * 4);
    int*   csr    = (int*)alloc((size_t)tot * 4);
    float* h1     = (float*)alloc((size_t)n * 512 * 4);
    float* x2     = (float*)alloc((size_t)n * 512 * 4);
    float* as1    = (float*)alloc((size_t)n * 8 * 4);
    float* ad1    = (float*)alloc((size_t)n * 8 * 4);
    float* h2     = (float*)alloc((size_t)n * 2 * 4);
    float* as2v   = (float*)alloc((size_t)n * 4);
    float* ad2v   = (float*)alloc((size_t)n * 4);

    int eb = (tot + 255) / 256;
    int zb = (n + 255) / 256;
    k_zero<<<zb, 256, 0, stream>>>(deg, n);
    k_count<<<eb, 256, 0, stream>>>(ei, deg, E_, n);
    k_scan<<<1, 1024, 0, stream>>>(deg, offs, cursor, n);
    k_scatter<<<eb, 256, 0, stream>>>(ei, cursor, csr, E_, n);

    dim3 g1((n + 63) / 64, 8);
    k_gemm1<<<g1, 256, 0, stream>>>(x, W1, h1, n);

    int nb = (n + 3) / 4;
    k_alpha1<<<nb, 256, 0, stream>>>(h1, a_src1, a_dst1, as1, ad1, n);
    k_agg1<<<nb, 256, 0, stream>>>(h1, as1, ad1, b1, offs, csr, x2, n);
    k_l2prep<<<nb, 256, 0, stream>>>(x2, W2, a_src2, a_dst2, h2, as2v, ad2v, n);
    k_agg2<<<nb, 256, 0, stream>>>(h2, as2v, ad2v, b2, offs, csr, out, n);
}

// Round 2
// 466.194 us; speedup vs baseline: 1.3343x; 1.3343x over previous
//
#include <hip/hip_runtime.h>
#include <hip/hip_bf16.h>

#define NEG 0.2f

typedef __attribute__((ext_vector_type(8))) short bf16x8;
typedef __attribute__((ext_vector_type(4))) float f32x4;

static __device__ __forceinline__ unsigned short f2bf(float f) {
    union { float f; unsigned u; } v; v.f = f;
    unsigned r = v.u + 0x7fff + ((v.u >> 16) & 1);
    return (unsigned short)(r >> 16);
}
static __device__ __forceinline__ float bf_lo(unsigned u) {  // low ushort -> float
    return __uint_as_float(u << 16);
}
static __device__ __forceinline__ float bf_hi(unsigned u) {  // high ushort -> float
    return __uint_as_float(u & 0xffff0000u);
}

// ---------------------------------------------------------------- CSR build
__global__ void k_zero(int* __restrict__ p, int n) {
    int i = blockIdx.x * 256 + threadIdx.x;
    if (i < n) p[i] = 0;
}

__global__ void k_count(const int* __restrict__ ei, int* __restrict__ deg,
                        int E_, int n) {
    int e = blockIdx.x * 256 + threadIdx.x;
    int tot = E_ + n;
    if (e >= tot) return;
    int d = (e < E_) ? ei[E_ + e] : (e - E_);
    atomicAdd(&deg[d], 1);
}

__global__ __launch_bounds__(1024) void k_scan(const int* __restrict__ deg,
                                               int* __restrict__ offs,
                                               int* __restrict__ cursor, int n) {
    __shared__ int wsum[16];
    __shared__ int carry_s;
    int tid = threadIdx.x, lane = tid & 63, w = tid >> 6;
    if (tid == 0) carry_s = 0;
    __syncthreads();
    for (int base = 0; base < n; base += 1024) {
        int i = base + tid;
        int val = (i < n) ? deg[i] : 0;
        int incl = val;
        #pragma unroll
        for (int off = 1; off < 64; off <<= 1) {
            int t = __shfl_up(incl, off, 64);
            if (lane >= off) incl += t;
        }
        if (lane == 63) wsum[w] = incl;
        __syncthreads();
        int carry = carry_s;
        if (w == 0) {
            int s = (lane < 16) ? wsum[lane] : 0;
            #pragma unroll
            for (int off = 1; off < 16; off <<= 1) {
                int t = __shfl_up(s, off, 64);
                if (lane >= off) s += t;
            }
            if (lane < 16) wsum[lane] = s;
        }
        __syncthreads();
        int woff = (w > 0) ? wsum[w - 1] : 0;
        int excl = carry + woff + incl - val;
        if (i < n) { offs[i] = excl; cursor[i] = excl; }
        __syncthreads();
        if (tid == 0) carry_s = carry + wsum[15];
        __syncthreads();
    }
    if (threadIdx.x == 0) offs[n] = carry_s;
}

__global__ void k_scatter(const int* __restrict__ ei, int* __restrict__ cursor,
                          int* __restrict__ csr, int E_, int n) {
    int e = blockIdx.x * 256 + threadIdx.x;
    int tot = E_ + n;
    if (e >= tot) return;
    int s, d;
    if (e < E_) { s = ei[e]; d = ei[E_ + e]; } else { s = d = e - E_; }
    int pos = atomicAdd(&cursor[d], 1);
    csr[pos] = s;
}

// ---------------------------------------------------------------- casts
__global__ void k_cast_x(const float* __restrict__ x, unsigned short* __restrict__ xb,
                         int nelem, int nelem_pad) {
    int i = (blockIdx.x * 256 + threadIdx.x) * 4;
    if (i >= nelem_pad) return;
    float4 v = (i < nelem) ? *(const float4*)(x + i) : make_float4(0, 0, 0, 0);
    ushort4 o;
    o.x = f2bf(v.x); o.y = f2bf(v.y); o.z = f2bf(v.z); o.w = f2bf(v.w);
    *(ushort4*)(xb + i) = o;
}

// W1 [128][512] -> W1t bf16 [512][128]
__global__ void k_cast_wt(const float* __restrict__ W, unsigned short* __restrict__ wt) {
    int i = blockIdx.x * 256 + threadIdx.x;   // 65536
    int c = i >> 7, k = i & 127;
    wt[i] = f2bf(W[k * 512 + c]);
}

// ---------------------------------------------------------------- GEMM1 (MFMA)
// h1b[n,512](bf16) = x[n,128] @ W1[128,512]; alpha scores fused (fp32 accums).
// Block: 256 thr = 4 waves; 64 rows x 64 cols (one head j = blockIdx.y).
// Wave w: 16-row strip. mfma 16x16x32: A[m=lane&15][k=q*8+jj], B[n=lane&15][k=q*8+jj],
// D col=lane&15, row=q*4+reg (q=lane>>4).
__global__ __launch_bounds__(256) void k_gemm1(const unsigned short* __restrict__ xb,
                                               const unsigned short* __restrict__ w1t,
                                               const float* __restrict__ a_src,
                                               const float* __restrict__ a_dst,
                                               unsigned short* __restrict__ h1b,
                                               float* __restrict__ as1,
                                               float* __restrict__ ad1, int n) {
    int tid = threadIdx.x;
    int wave = tid >> 6, lane = tid & 63;
    int l15 = lane & 15, q = lane >> 4;
    int j = blockIdx.y;
    int col0 = j * 64;
    int row0 = blockIdx.x * 64 + wave * 16;

    f32x4 acc[4] = {};   // acc[t] : col-tile t (cols col0+16t .. +16)
    const unsigned short* ap = xb + (size_t)(row0 + l15) * 128 + q * 8;
    #pragma unroll
    for (int kb = 0; kb < 4; kb++) {
        bf16x8 af = *(const bf16x8*)(ap + kb * 32);
        #pragma unroll
        for (int t = 0; t < 4; t++) {
            const unsigned short* bp =
                w1t + (size_t)(col0 + t * 16 + l15) * 128 + kb * 32 + q * 8;
            bf16x8 bfv = *(const bf16x8*)bp;
            acc[t] = __builtin_amdgcn_mfma_f32_16x16x32_bf16(af, bfv, acc[t], 0, 0, 0);
        }
    }
    // store h1 in bf16
    #pragma unroll
    for (int t = 0; t < 4; t++) {
        #pragma unroll
        for (int r = 0; r < 4; r++) {
            int row = row0 + q * 4 + r;
            if (row < n)
                h1b[(size_t)row * 512 + col0 + t * 16 + l15] = f2bf(acc[t][r]);
        }
    }
    // fused alpha: as1[row,j] = sum_c acc * a_src[j,c]  (fp32 exact)
    float asv[4], adv[4];
    #pragma unroll
    for (int t = 0; t < 4; t++) {
        asv[t] = a_src[j * 64 + t * 16 + l15];
        adv[t] = a_dst[j * 64 + t * 16 + l15];
    }
    float ps[4], pd[4];
    #pragma unroll
    for (int r = 0; r < 4; r++) {
        ps[r] = acc[0][r] * asv[0] + acc[1][r] * asv[1]
              + acc[2][r] * asv[2] + acc[3][r] * asv[3];
        pd[r] = acc[0][r] * adv[0] + acc[1][r] * adv[1]
              + acc[2][r] * adv[2] + acc[3][r] * adv[3];
        #pragma unroll
        for (int off = 1; off < 16; off <<= 1) {  // reduce within quad (16 lanes)
            ps[r] += __shfl_xor(ps[r], off, 64);
            pd[r] += __shfl_xor(pd[r], off, 64);
        }
    }
    if (l15 < 4) {
        int r = l15;
        float vps = ps[0], vpd = pd[0];
        if (r == 1) { vps = ps[1]; vpd = pd[1]; }
        if (r == 2) { vps = ps[2]; vpd = pd[2]; }
        if (r == 3) { vps = ps[3]; vpd = pd[3]; }
        int row = row0 + q * 4 + r;
        if (row < n) { as1[row * 8 + j] = vps; ad1[row * 8 + j] = vpd; }
    }
}

// ---------------------------------------------------------------- agg layer 1
// One wave per dst node, single pass, unnormalized exp (|e| is O(10), fp32-safe).
// Lane covers channels [8*lane, 8*lane+8), head = lane>>3. Epilogue: /s, +b1, ELU.
__global__ __launch_bounds__(256) void k_agg1(const unsigned short* __restrict__ h1b,
                                              const float* __restrict__ as1,
                                              const float* __restrict__ ad1,
                                              const float* __restrict__ b1,
                                              const int* __restrict__ offs,
                                              const int* __restrict__ csr,
                                              unsigned short* __restrict__ x2b, int n) {
    int lane = threadIdx.x & 63;
    int v = blockIdx.x * 4 + (threadIdx.x >> 6);
    if (v >= n) return;
    int head = lane >> 3, c = lane * 8;
    int s0 = offs[v], s1 = offs[v + 1];
    float adh = ad1[v * 8 + head];
    float s = 0.f;
    float acc[8] = {};
    for (int i = s0; i < s1; i++) {
        int u = csr[i];
        float e = as1[u * 8 + head] + adh;
        e = (e >= 0.f) ? e : NEG * e;
        float w = __expf(e);
        s += w;
        uint4 hv = *(const uint4*)(h1b + (size_t)u * 512 + c);
        acc[0] = fmaf(w, bf_lo(hv.x), acc[0]);
        acc[1] = fmaf(w, bf_hi(hv.x), acc[1]);
        acc[2] = fmaf(w, bf_lo(hv.y), acc[2]);
        acc[3] = fmaf(w, bf_hi(hv.y), acc[3]);
        acc[4] = fmaf(w, bf_lo(hv.z), acc[4]);
        acc[5] = fmaf(w, bf_hi(hv.z), acc[5]);
        acc[6] = fmaf(w, bf_lo(hv.w), acc[6]);
        acc[7] = fmaf(w, bf_hi(hv.w), acc[7]);
    }
    float inv = 1.0f / s;
    float4 ba = *(const float4*)(b1 + c);
    float4 bb = *(const float4*)(b1 + c + 4);
    float o[8] = {acc[0] * inv + ba.x, acc[1] * inv + ba.y,
                  acc[2] * inv + ba.z, acc[3] * inv + ba.w,
                  acc[4] * inv + bb.x, acc[5] * inv + bb.y,
                  acc[6] * inv + bb.z, acc[7] * inv + bb.w};
    #pragma unroll
    for (int jj = 0; jj < 8; jj++)
        o[jj] = (o[jj] > 0.f) ? o[jj] : (__expf(o[jj]) - 1.0f);
    uint4 ov;
    ov.x = (unsigned)f2bf(o[0]) | ((unsigned)f2bf(o[1]) << 16);
    ov.y = (unsigned)f2bf(o[2]) | ((unsigned)f2bf(o[3]) << 16);
    ov.z = (unsigned)f2bf(o[4]) | ((unsigned)f2bf(o[5]) << 16);
    ov.w = (unsigned)f2bf(o[6]) | ((unsigned)f2bf(o[7]) << 16);
    *(uint4*)(x2b + (size_t)v * 512 + c) = ov;
}

// ---------------------------------------------------------------- layer2 prep
__global__ __launch_bounds__(256) void k_l2prep(const unsigned short* __restrict__ x2b,
                                                const float* __restrict__ W2,
                                                const float* __restrict__ a_src2,
                                                const float* __restrict__ a_dst2,
                                                float* __restrict__ h2,
                                                float* __restrict__ as2,
                                                float* __restrict__ ad2, int n) {
    int lane = threadIdx.x & 63;
    int v = blockIdx.x * 4 + (threadIdx.x >> 6);
    if (v >= n) return;
    uint4 xv = *(const uint4*)(x2b + (size_t)v * 512 + lane * 8);
    float x0 = bf_lo(xv.x), x1 = bf_hi(xv.x), x2 = bf_lo(xv.y), x3 = bf_hi(xv.y);
    float x4 = bf_lo(xv.z), x5 = bf_hi(xv.z), x6 = bf_lo(xv.w), x7 = bf_hi(xv.w);
    int c = lane * 8;
    const float4* wp = (const float4*)(W2 + c * 2);
    float4 w0 = wp[0], w1 = wp[1], w2 = wp[2], w3 = wp[3];
    float p0 = x0 * w0.x + x1 * w0.z + x2 * w1.x + x3 * w1.z
             + x4 * w2.x + x5 * w2.z + x6 * w3.x + x7 * w3.z;
    float p1 = x0 * w0.y + x1 * w0.w + x2 * w1.y + x3 * w1.w
             + x4 * w2.y + x5 * w2.w + x6 * w3.y + x7 * w3.w;
    #pragma unroll
    for (int off = 1; off < 64; off <<= 1) {
        p0 += __shfl_xor(p0, off, 64);
        p1 += __shfl_xor(p1, off, 64);
    }
    if (lane == 0) {
        h2[2 * v] = p0; h2[2 * v + 1] = p1;
        as2[v] = p0 * a_src2[0] + p1 * a_src2[1];
        ad2[v] = p0 * a_dst2[0] + p1 * a_dst2[1];
    }
}

// ---------------------------------------------------------------- agg layer 2
// Lane-parallel edges, unnormalized exp, 3 butterfly reductions.
__global__ __launch_bounds__(256) void k_agg2(const float* __restrict__ h2,
                                              const float* __restrict__ as2,
                                              const float* __restrict__ ad2,
                                              const float* __restrict__ b2,
                                              const int* __restrict__ offs,
                                              const int* __restrict__ csr,
                                              float* __restrict__ out, int n) {
    int lane = threadIdx.x & 63;
    int v = blockIdx.x * 4 + (threadIdx.x >> 6);
    if (v >= n) return;
    int s0 = offs[v], s1 = offs[v + 1];
    float adv = ad2[v];
    float s = 0.f, a0 = 0.f, a1 = 0.f;
    for (int i = s0 + lane; i < s1; i += 64) {
        int u = csr[i];
        float e = as2[u] + adv;
        e = (e >= 0.f) ? e : NEG * e;
        float w = __expf(e);
        float2 h = *(const float2*)(h2 + 2 * u);
        s += w;
        a0 = fmaf(w, h.x, a0);
        a1 = fmaf(w, h.y, a1);
    }
    #pragma unroll
    for (int off = 1; off < 64; off <<= 1) {
        s  += __shfl_xor(s, off, 64);
        a0 += __shfl_xor(a0, off, 64);
        a1 += __shfl_xor(a1, off, 64);
    }
    if (lane == 0) {
        float inv = 1.0f / s;
        out[2 * v]     = a0 * inv + b2[0];
        out[2 * v + 1] = a1 * inv + b2[1];
    }
}

// ---------------------------------------------------------------- launch
extern "C" void kernel_launch(void* const* d_in, const int* in_sizes, int n_in,
                              void* d_out, int out_size, void* d_ws, size_t ws_size,
                              hipStream_t stream) {
    const float* x      = (const float*)d_in[0];
    const int*   ei     = (const int*)d_in[1];
    const float* W1     = (const float*)d_in[2];
    const float* a_src1 = (const float*)d_in[3];
    const float* a_dst1 = (const float*)d_in[4];
    const float* b1     = (const float*)d_in[5];
    const float* W2     = (const float*)d_in[6];
    const float* a_src2 = (const float*)d_in[7];
    const float* a_dst2 = (const float*)d_in[8];
    const float* b2     = (const float*)d_in[9];
    float* out = (float*)d_out;

    int n  = in_sizes[0] / 128;   // 50000
    int E_ = in_sizes[1] / 2;     // 800000
    int tot = E_ + n;
    int rblk = (n + 63) / 64;     // 782
    int npad = rblk * 64;         // 50048

    char* w = (char*)d_ws;
    auto alloc = [&](size_t bytes) {
        char* p = w; w += (bytes + 255) & ~(size_t)255; return p;
    };
    int*            deg    = (int*)alloc((size_t)n * 4);
    int*            offs   = (int*)alloc((size_t)(n + 1) * 4);
    int*            cursor = (int*)alloc((size_t)n * 4);
    int*            csr    = (int*)alloc((size_t)tot * 4);
    unsigned short* xb     = (unsigned short*)alloc((size_t)npad * 128 * 2);
    unsigned short* w1t    = (unsigned short*)alloc((size_t)512 * 128 * 2);
    unsigned short* h1b    = (unsigned short*)alloc((size_t)npad * 512 * 2);
    unsigned short* x2b    = (unsigned short*)alloc((size_t)npad * 512 * 2);
    float*          as1    = (float*)alloc((size_t)n * 8 * 4);
    float*          ad1    = (float*)alloc((size_t)n * 8 * 4);
    float*          h2     = (float*)alloc((size_t)n * 2 * 4);
    float*          as2v   = (float*)alloc((size_t)n * 4);
    float*          ad2v   = (float*)alloc((size_t)n * 4);

    int eb = (tot + 255) / 256;
    int zb = (n + 255) / 256;
    k_zero<<<zb, 256, 0, stream>>>(deg, n);
    k_count<<<eb, 256, 0, stream>>>(ei, deg, E_, n);
    k_scan<<<1, 1024, 0, stream>>>(deg, offs, cursor, n);
    k_scatter<<<eb, 256, 0, stream>>>(ei, cursor, csr, E_, n);

    int xel = n * 128, xelp = npad * 128;
    k_cast_x<<<(xelp / 4 + 255) / 256, 256, 0, stream>>>(x, xb, xel, xelp);
    k_cast_wt<<<(512 * 128) / 256, 256, 0, stream>>>(W1, w1t);

    dim3 g1(rblk, 8);
    k_gemm1<<<g1, 256, 0, stream>>>(xb, w1t, a_src1, a_dst1, h1b, as1, ad1, n);

    int nb = (n + 3) / 4;
    k_agg1<<<nb, 256, 0, stream>>>(h1b, as1, ad1, b1, offs, csr, x2b, n);
    k_l2prep<<<nb, 256, 0, stream>>>(x2b, W2, a_src2, a_dst2, h2, as2v, ad2v, n);
    k_agg2<<<nb, 256, 0, stream>>>(h2, as2v, ad2v, b2, offs, csr, out, n);
}

// Round 5
// 427.036 us; speedup vs baseline: 1.4566x; 1.0917x over previous
//
#include <hip/hip_runtime.h>
#include <hip/hip_bf16.h>

#define NEG 0.2f

typedef __attribute__((ext_vector_type(8))) short bf16x8;
typedef __attribute__((ext_vector_type(4))) float f32x4;

static __device__ __forceinline__ unsigned short f2bf(float f) {
    union { float f; unsigned u; } v; v.f = f;
    unsigned r = v.u + 0x7fff + ((v.u >> 16) & 1);
    return (unsigned short)(r >> 16);
}
static __device__ __forceinline__ float bf2f(unsigned short h) {
    return __uint_as_float((unsigned)h << 16);
}
static __device__ __forceinline__ float bf_lo(unsigned u) {
    return __uint_as_float(u << 16);
}
static __device__ __forceinline__ float bf_hi(unsigned u) {
    return __uint_as_float(u & 0xffff0000u);
}

// ---------------------------------------------------------------- init
__global__ void k_zero(int* __restrict__ deg, float* __restrict__ h2,
                       int* __restrict__ total, int n) {
    int i = blockIdx.x * 256 + threadIdx.x;
    if (i < n) deg[i] = 0;
    if (i < 2 * n) h2[i] = 0.f;
    if (i == 0) *total = 0;
}

__global__ void k_count(const int* __restrict__ ei, int* __restrict__ deg,
                        int E_, int n) {
    int e = blockIdx.x * 256 + threadIdx.x;
    int tot = E_ + n;
    if (e >= tot) return;
    int d = (e < E_) ? ei[E_ + e] : (e - E_);
    atomicAdd(&deg[d], 1);
}

// parallel offset assignment (order-free CSR: offs need not be monotone)
__global__ void k_assign(const int* __restrict__ deg, int* __restrict__ offs,
                         int* __restrict__ cursor, int* __restrict__ total, int n) {
    int v = blockIdx.x * 256 + threadIdx.x;
    if (v >= n) return;
    int d = deg[v];
    int base = atomicAdd(total, d);
    offs[v] = base; cursor[v] = base;
}

__global__ void k_scatter(const int* __restrict__ ei, int* __restrict__ cursor,
                          int* __restrict__ csr, int E_, int n) {
    int e = blockIdx.x * 256 + threadIdx.x;
    int tot = E_ + n;
    if (e >= tot) return;
    int s, d;
    if (e < E_) { s = ei[e]; d = ei[E_ + e]; } else { s = d = e - E_; }
    int pos = atomicAdd(&cursor[d], 1);
    csr[pos] = s;
}

// ---------------------------------------------------------------- casts
__global__ void k_cast_x(const float* __restrict__ x, unsigned short* __restrict__ xb,
                         int nelem, int nelem_pad) {
    int i = (blockIdx.x * 256 + threadIdx.x) * 4;
    if (i >= nelem_pad) return;
    float4 v = (i < nelem) ? *(const float4*)(x + i) : make_float4(0, 0, 0, 0);
    ushort4 o;
    o.x = f2bf(v.x); o.y = f2bf(v.y); o.z = f2bf(v.z); o.w = f2bf(v.w);
    *(ushort4*)(xb + i) = o;
}

// W1 [128][512] -> W1t bf16 [512][128]
__global__ void k_cast_wt(const float* __restrict__ W, unsigned short* __restrict__ wt) {
    int i = blockIdx.x * 256 + threadIdx.x;   // 65536
    int c = i >> 7, k = i & 127;
    wt[i] = f2bf(W[k * 512 + c]);
}

// c[col,k] = sum_cc W1[k, h*64+cc] * a[h,cc]; col = h (+8 for dst).
// hi/lo bf16 split for near-fp32 MFMA scores.
__global__ void k_prep_c(const float* __restrict__ W1, const float* __restrict__ a_src,
                         const float* __restrict__ a_dst,
                         unsigned short* __restrict__ cbhi,
                         unsigned short* __restrict__ cblo) {
    int t = blockIdx.x * 256 + threadIdx.x;   // 2048
    if (t >= 2048) return;
    int which = t >> 10, rem = t & 1023;
    int h = rem >> 7, k = rem & 127;
    const float* a = which ? a_dst : a_src;
    float s = 0.f;
    #pragma unroll 8
    for (int cc = 0; cc < 64; cc++)
        s = fmaf(W1[k * 512 + h * 64 + cc], a[h * 64 + cc], s);
    unsigned short hi = f2bf(s);
    unsigned short lo = f2bf(s - bf2f(hi));
    cbhi[(which * 8 + h) * 128 + k] = hi;
    cblo[(which * 8 + h) * 128 + k] = lo;
}

// ---------------------------------------------------------------- alpha (MFMA, hi/lo)
// [as1|ad1][row, 0..16] = x[row,128] @ c^T with split-bf16 precision (~fp32).
__global__ __launch_bounds__(256) void k_alpha(const float* __restrict__ x,
                                               const unsigned short* __restrict__ cbhi,
                                               const unsigned short* __restrict__ cblo,
                                               float* __restrict__ as1,
                                               float* __restrict__ ad1, int n) {
    int tid = threadIdx.x, wave = tid >> 6, lane = tid & 63;
    int l15 = lane & 15, q = lane >> 4;
    int row0 = blockIdx.x * 64 + wave * 16;
    int rr = row0 + l15; if (rr > n - 1) rr = n - 1;   // clamp (guarded at store)
    f32x4 acc = {};
    const float* ap = x + (size_t)rr * 128 + q * 8;
    const unsigned short* bph = cbhi + (size_t)l15 * 128 + q * 8;
    const unsigned short* bpl = cblo + (size_t)l15 * 128 + q * 8;
    #pragma unroll
    for (int kb = 0; kb < 4; kb++) {
        float4 v0 = *(const float4*)(ap + kb * 32);
        float4 v1 = *(const float4*)(ap + kb * 32 + 4);
        float xv[8] = {v0.x, v0.y, v0.z, v0.w, v1.x, v1.y, v1.z, v1.w};
        bf16x8 ahi, alo;
        #pragma unroll
        for (int j = 0; j < 8; j++) {
            unsigned short h = f2bf(xv[j]);
            ahi[j] = (short)h;
            alo[j] = (short)f2bf(xv[j] - bf2f(h));
        }
        bf16x8 bh = *(const bf16x8*)(bph + kb * 32);
        bf16x8 bl = *(const bf16x8*)(bpl + kb * 32);
        acc = __builtin_amdgcn_mfma_f32_16x16x32_bf16(ahi, bh, acc, 0, 0, 0);
        acc = __builtin_amdgcn_mfma_f32_16x16x32_bf16(ahi, bl, acc, 0, 0, 0);
        acc = __builtin_amdgcn_mfma_f32_16x16x32_bf16(alo, bh, acc, 0, 0, 0);
    }
    #pragma unroll
    for (int r = 0; r < 4; r++) {
        int row = row0 + q * 4 + r;
        if (row < n) {
            if (l15 < 8) as1[row * 8 + l15] = acc[r];
            else         ad1[row * 8 + (l15 - 8)] = acc[r];
        }
    }
}

// ---------------------------------------------------------------- agg in x-space
// aggx[v,h,:] = (1/s) sum_u w_uvh * x_u, stored as hi/lo bf16 split (~fp32).
// One wave per dst node. lane = h*8+j: head h, channels [16j,16j+16).
__global__ __launch_bounds__(256) void k_aggx(const unsigned short* __restrict__ xb,
                                              const float* __restrict__ as1,
                                              const float* __restrict__ ad1,
                                              const int* __restrict__ offs,
                                              const int* __restrict__ deg,
                                              const int* __restrict__ csr,
                                              unsigned short* __restrict__ agghi,
                                              unsigned short* __restrict__ agglo, int n) {
    int lane = threadIdx.x & 63;
    int v = blockIdx.x * 4 + (threadIdx.x >> 6);
    if (v >= n) return;
    int h = lane >> 3, j = lane & 7;
    int s0 = offs[v], s1 = s0 + deg[v];
    float adh = ad1[v * 8 + h];
    float s = 0.f;
    float acc[16] = {};
    for (int i = s0; i < s1; i++) {
        int u = csr[i];
        float e = as1[u * 8 + h] + adh;
        e = (e >= 0.f) ? e : NEG * e;
        float w = __expf(e);
        s += w;
        const uint4* xp = (const uint4*)(xb + (size_t)u * 128 + j * 16);
        uint4 xa = xp[0], xc = xp[1];
        acc[0]  = fmaf(w, bf_lo(xa.x), acc[0]);
        acc[1]  = fmaf(w, bf_hi(xa.x), acc[1]);
        acc[2]  = fmaf(w, bf_lo(xa.y), acc[2]);
        acc[3]  = fmaf(w, bf_hi(xa.y), acc[3]);
        acc[4]  = fmaf(w, bf_lo(xa.z), acc[4]);
        acc[5]  = fmaf(w, bf_hi(xa.z), acc[5]);
        acc[6]  = fmaf(w, bf_lo(xa.w), acc[6]);
        acc[7]  = fmaf(w, bf_hi(xa.w), acc[7]);
        acc[8]  = fmaf(w, bf_lo(xc.x), acc[8]);
        acc[9]  = fmaf(w, bf_hi(xc.x), acc[9]);
        acc[10] = fmaf(w, bf_lo(xc.y), acc[10]);
        acc[11] = fmaf(w, bf_hi(xc.y), acc[11]);
        acc[12] = fmaf(w, bf_lo(xc.z), acc[12]);
        acc[13] = fmaf(w, bf_hi(xc.z), acc[13]);
        acc[14] = fmaf(w, bf_lo(xc.w), acc[14]);
        acc[15] = fmaf(w, bf_hi(xc.w), acc[15]);
    }
    float inv = 1.0f / s;
    uint4 ohi, olo;
    unsigned* ph = (unsigned*)&ohi;
    unsigned* pl = (unsigned*)&olo;
    #pragma unroll
    for (int p = 0; p < 4; p++) {
        float v0 = acc[2 * p] * inv, v1 = acc[2 * p + 1] * inv;
        unsigned short h0 = f2bf(v0), h1v = f2bf(v1);
        unsigned short l0 = f2bf(v0 - bf2f(h0)), l1 = f2bf(v1 - bf2f(h1v));
        ph[p] = (unsigned)h0 | ((unsigned)h1v << 16);
        pl[p] = (unsigned)l0 | ((unsigned)l1 << 16);
    }
    size_t base = (size_t)v * 1024 + h * 128 + j * 16;
    *(uint4*)(agghi + base) = ohi;
    *(uint4*)(agglo + base) = olo;
    uint4 ohi2, olo2;
    unsigned* ph2 = (unsigned*)&ohi2;
    unsigned* pl2 = (unsigned*)&olo2;
    #pragma unroll
    for (int p = 0; p < 4; p++) {
        float v0 = acc[8 + 2 * p] * inv, v1 = acc[8 + 2 * p + 1] * inv;
        unsigned short h0 = f2bf(v0), h1v = f2bf(v1);
        unsigned short l0 = f2bf(v0 - bf2f(h0)), l1 = f2bf(v1 - bf2f(h1v));
        ph2[p] = (unsigned)h0 | ((unsigned)h1v << 16);
        pl2[p] = (unsigned)l0 | ((unsigned)l1 << 16);
    }
    *(uint4*)(agghi + base + 8) = ohi2;
    *(uint4*)(agglo + base + 8) = olo2;
}

// ---------------------------------------------------------------- GEMM2 (MFMA, hi/lo A)
// per head h: val[row,col] = ELU((agghi+agglo)[row,h,:]@W1_h[:,col] + b1); project
// through W2, atomicAdd into h2[row,0:2]. x2 never materialized.
__global__ __launch_bounds__(256) void k_gemm2(const unsigned short* __restrict__ agghi,
                                               const unsigned short* __restrict__ agglo,
                                               const unsigned short* __restrict__ w1t,
                                               const float* __restrict__ b1,
                                               const float* __restrict__ W2,
                                               float* __restrict__ h2, int n) {
    int tid = threadIdx.x, wave = tid >> 6, lane = tid & 63;
    int l15 = lane & 15, q = lane >> 4;
    int h = blockIdx.y, col0 = h * 64;
    int row0 = blockIdx.x * 64 + wave * 16;
    f32x4 acc[4] = {};
    size_t abase = (size_t)(row0 + l15) * 1024 + h * 128 + q * 8;
    #pragma unroll
    for (int kb = 0; kb < 4; kb++) {
        bf16x8 ahi = *(const bf16x8*)(agghi + abase + kb * 32);
        bf16x8 alo = *(const bf16x8*)(agglo + abase + kb * 32);
        #pragma unroll
        for (int t = 0; t < 4; t++) {
            const unsigned short* bp =
                w1t + (size_t)(col0 + t * 16 + l15) * 128 + kb * 32 + q * 8;
            bf16x8 bf = *(const bf16x8*)bp;
            acc[t] = __builtin_amdgcn_mfma_f32_16x16x32_bf16(ahi, bf, acc[t], 0, 0, 0);
            acc[t] = __builtin_amdgcn_mfma_f32_16x16x32_bf16(alo, bf, acc[t], 0, 0, 0);
        }
    }
    float p0[4] = {}, p1[4] = {};
    #pragma unroll
    for (int t = 0; t < 4; t++) {
        int col = col0 + t * 16 + l15;
        float bb = b1[col];
        float w20 = W2[col * 2], w21 = W2[col * 2 + 1];
        #pragma unroll
        for (int r = 0; r < 4; r++) {
            float val = acc[t][r] + bb;
            val = (val > 0.f) ? val : (__expf(val) - 1.0f);
            p0[r] = fmaf(val, w20, p0[r]);
            p1[r] = fmaf(val, w21, p1[r]);
        }
    }
    #pragma unroll
    for (int r = 0; r < 4; r++) {
        #pragma unroll
        for (int off = 1; off < 16; off <<= 1) {
            p0[r] += __shfl_xor(p0[r], off, 64);
            p1[r] += __shfl_xor(p1[r], off, 64);
        }
    }
    if (l15 < 4) {
        float q0 = p0[0], q1 = p1[0];
        if (l15 == 1) { q0 = p0[1]; q1 = p1[1]; }
        if (l15 == 2) { q0 = p0[2]; q1 = p1[2]; }
        if (l15 == 3) { q0 = p0[3]; q1 = p1[3]; }
        int row = row0 + q * 4 + l15;
        if (row < n) {
            atomicAdd(&h2[2 * row],     q0);
            atomicAdd(&h2[2 * row + 1], q1);
        }
    }
}

// ---------------------------------------------------------------- agg layer 2
__global__ __launch_bounds__(256) void k_agg2(const float* __restrict__ h2,
                                              const float* __restrict__ a_src2,
                                              const float* __restrict__ a_dst2,
                                              const float* __restrict__ b2,
                                              const int* __restrict__ offs,
                                              const int* __restrict__ deg,
                                              const int* __restrict__ csr,
                                              float* __restrict__ out, int n) {
    int lane = threadIdx.x & 63;
    int v = blockIdx.x * 4 + (threadIdx.x >> 6);
    if (v >= n) return;
    int s0 = offs[v], s1 = s0 + deg[v];
    float sa0 = a_src2[0], sa1 = a_src2[1];
    float da0 = a_dst2[0], da1 = a_dst2[1];
    float2 hv = *(const float2*)(h2 + 2 * v);
    float adv = hv.x * da0 + hv.y * da1;
    float s = 0.f, a0 = 0.f, a1 = 0.f;
    for (int i = s0 + lane; i < s1; i += 64) {
        int u = csr[i];
        float2 hu = *(const float2*)(h2 + 2 * u);
        float e = hu.x * sa0 + hu.y * sa1 + adv;
        e = (e >= 0.f) ? e : NEG * e;
        float w = __expf(e);
        s += w;
        a0 = fmaf(w, hu.x, a0);
        a1 = fmaf(w, hu.y, a1);
    }
    #pragma unroll
    for (int off = 1; off < 64; off <<= 1) {
        s  += __shfl_xor(s, off, 64);
        a0 += __shfl_xor(a0, off, 64);
        a1 += __shfl_xor(a1, off, 64);
    }
    if (lane == 0) {
        float inv = 1.0f / s;
        out[2 * v]     = a0 * inv + b2[0];
        out[2 * v + 1] = a1 * inv + b2[1];
    }
}

// ---------------------------------------------------------------- launch
extern "C" void kernel_launch(void* const* d_in, const int* in_sizes, int n_in,
                              void* d_out, int out_size, void* d_ws, size_t ws_size,
                              hipStream_t stream) {
    const float* x      = (const float*)d_in[0];
    const int*   ei     = (const int*)d_in[1];
    const float* W1     = (const float*)d_in[2];
    const float* a_src1 = (const float*)d_in[3];
    const float* a_dst1 = (const float*)d_in[4];
    const float* b1     = (const float*)d_in[5];
    const float* W2     = (const float*)d_in[6];
    const float* a_src2 = (const float*)d_in[7];
    const float* a_dst2 = (const float*)d_in[8];
    const float* b2     = (const float*)d_in[9];
    float* out = (float*)d_out;

    int n  = in_sizes[0] / 128;   // 50000
    int E_ = in_sizes[1] / 2;     // 800000
    int tot = E_ + n;
    int rblk = (n + 63) / 64;     // 782
    int npad = rblk * 64;         // 50048

    char* w = (char*)d_ws;
    auto alloc = [&](size_t bytes) {
        char* p = w; w += (bytes + 255) & ~(size_t)255; return p;
    };
    int*            deg    = (int*)alloc((size_t)n * 4);
    int*            offs   = (int*)alloc((size_t)n * 4);
    int*            cursor = (int*)alloc((size_t)n * 4);
    int*            total  = (int*)alloc(256);
    int*            csr    = (int*)alloc((size_t)tot * 4);
    unsigned short* xb     = (unsigned short*)alloc((size_t)npad * 128 * 2);
    unsigned short* w1t    = (unsigned short*)alloc((size_t)512 * 128 * 2);
    unsigned short* cbhi   = (unsigned short*)alloc((size_t)16 * 128 * 2);
    unsigned short* cblo   = (unsigned short*)alloc((size_t)16 * 128 * 2);
    float*          as1    = (float*)alloc((size_t)n * 8 * 4);
    float*          ad1    = (float*)alloc((size_t)n * 8 * 4);
    unsigned short* agghi  = (unsigned short*)alloc((size_t)npad * 1024 * 2);
    unsigned short* agglo  = (unsigned short*)alloc((size_t)npad * 1024 * 2);
    float*          h2     = (float*)alloc((size_t)n * 2 * 4);

    int eb = (tot + 255) / 256;
    int zb = (2 * n + 255) / 256;
    int nb256 = (n + 255) / 256;
    k_zero<<<zb, 256, 0, stream>>>(deg, h2, total, n);
    k_count<<<eb, 256, 0, stream>>>(ei, deg, E_, n);
    k_assign<<<nb256, 256, 0, stream>>>(deg, offs, cursor, total, n);
    k_scatter<<<eb, 256, 0, stream>>>(ei, cursor, csr, E_, n);

    int xel = n * 128, xelp = npad * 128;
    k_cast_x<<<(xelp / 4 + 255) / 256, 256, 0, stream>>>(x, xb, xel, xelp);
    k_cast_wt<<<(512 * 128) / 256, 256, 0, stream>>>(W1, w1t);
    k_prep_c<<<8, 256, 0, stream>>>(W1, a_src1, a_dst1, cbhi, cblo);

    k_alpha<<<rblk, 256, 0, stream>>>(x, cbhi, cblo, as1, ad1, n);

    int nb = (n + 3) / 4;
    k_aggx<<<nb, 256, 0, stream>>>(xb, as1, ad1, offs, deg, csr, agghi, agglo, n);

    dim3 g2(rblk, 8);
    k_gemm2<<<g2, 256, 0, stream>>>(agghi, agglo, w1t, b1, W2, h2, n);

    k_agg2<<<nb, 256, 0, stream>>>(h2, a_src2, a_dst2, b2, offs, deg, csr, out, n);
}